// Round 20
// baseline (70.181 us; speedup 1.0000x reference)
//
#include <hip/hip_runtime.h>

#define HOP 256
#define CUT 513
#define T_FRAMES 1021
#define N_SAMPLES 262144
#define BATCH 16
#define BLKS_PER_B 64             // 16 frames per block
#define NWG (BATCH * BLKS_PER_B)  // 1024, divisible by 8
#define FLAG_T 0.01f              // |im| flag threshold (fp32 FFT err ~2e-4)

// 6-bit bit reversal
__device__ __forceinline__ int bitrev6(int v) {
    return ((v & 1) << 5) | ((v & 2) << 3) | ((v & 4) << 1)
         | ((v & 8) >> 1) | ((v & 16) >> 3) | ((v & 32) >> 5);
}
// LDS slot for (k, tt in 0..15): stride 17 + XOR swizzle (<=2-way banks)
__device__ __forceinline__ int slot17(int k, int tt) {
    return 17 * k + (tt ^ ((k >> 4) & 15));
}
// W_1024^k as (cos,sin), arg in revolutions [R7-verified]
__device__ __forceinline__ float2 twid(float rev) {
    return make_float2(__builtin_amdgcn_cosf(rev), __builtin_amdgcn_sinf(rev));
}
__device__ __forceinline__ float2 cmulwf(float yr, float yi, float2 w) {
    return make_float2(yr * w.x + yi * w.y, yi * w.x - yr * w.y);
}
// fast atan2 [R13-verified]
__device__ __forceinline__ float fast_atan2f(float y, float x) {
    const float PI  = 3.14159265358979323846f;
    const float PI2 = 1.57079632679489661923f;
    float ay = __builtin_fabsf(y), ax = __builtin_fabsf(x);
    float mx = fmaxf(ax, ay), mn = fminf(ax, ay);
    float r  = mn * __builtin_amdgcn_rcpf(mx);
    float s  = r * r;
    float p  = r * (0.99997726f + s * (-0.33262347f + s * (0.19354346f
             + s * (-0.11643287f + s * (0.05265332f + s * (-0.01172120f))))));
    p = (ay > ax) ? (PI2 - p) : p;
    p = (x < 0.0f) ? (PI - p) : p;
    return __builtin_copysignf(p, y);
}
// fp64 (cos,sin) of 2*pi*e/1024 [R16-verified]
__device__ __forceinline__ double2 wexp64(int e) {
    const int d = e & 63, c = (e >> 6) & 3, a = (e >> 8) & 3;
    double xx = (6.2831853071795864769252867665590057684 / 1024.0) * (double)d;
    double x2 = xx * xx;
    double cc = 1.0 + x2 * (-0.5 + x2 * (1.0/24.0 + x2 * (-1.0/720.0
               + x2 * (1.0/40320.0 + x2 * (-1.0/3628800.0)))));
    double ss = xx * (1.0 + x2 * (-1.0/6.0 + x2 * (1.0/120.0 + x2 * (-1.0/5040.0
               + x2 * (1.0/362880.0 + x2 * (-1.0/39916800.0))))));
    double kc = (c == 0) ? 1.0
              : (c == 1) ? 0.92387953251128675612818318939679
              : (c == 2) ? 0.70710678118654752440084436210485
                         : 0.38268343236508977172845998403040;
    double ks = (c == 0) ? 0.0
              : (c == 1) ? 0.38268343236508977172845998403040
              : (c == 2) ? 0.70710678118654752440084436210485
                         : 0.92387953251128675612818318939679;
    double cr = cc * kc - ss * ks;
    double ci = ss * kc + cc * ks;
    double2 r;
    r.x = (a == 0) ? cr : ((a == 1) ? -ci : ((a == 2) ? -cr : ci));
    r.y = (a == 0) ? ci : ((a == 1) ?  cr : ((a == 2) ? -ci : -cr));
    return r;
}

__global__ __launch_bounds__(512, 2) void stft_fft_kernel(
    const float* __restrict__ x,
    const float* __restrict__ basis,
    float* __restrict__ out)
{
    __shared__ float smag[17 * CUT + 15];   // slot17-addressed, 16 t-columns
    __shared__ float sph[17 * CUT + 15];

    const int tid  = threadIdx.x;
    const int lane = tid & 63;
    const int wv   = tid >> 6;              // 0..7

    // XCD-chunked bijective swizzle (1024 % 8 == 0): 128 consecutive per XCD
    const int sb  = (blockIdx.x & 7) * (NWG / 8) + (blockIdx.x >> 3);
    const int b   = sb >> 6;                // batch
    const int blk = sb & 63;
    const int tb  = blk * 16;               // block's 16-frame t-base
    const int t0  = tb + 2 * wv;            // this wave's frame pair
    const bool active = (t0 < T_FRAMES);    // wave-uniform
    const bool has_b  = (t0 + 1 < T_FRAMES);
    const int ttA = 2 * wv;                 // wave's LDS columns

    const float* xptr = x + (size_t)b * N_SAMPLES + (size_t)t0 * HOP;
    const float* wrow = basis;              // row 0 == Hann window

    if (active) {
        // ---- split-load packing: rolling 12-reg window [R19-verified]
        float2 z[16];
        float IA = 0.f, IB = 0.f;
        double pA = 0.0, pB = 0.0;          // per-lane fp64 partial of sum(w*x)
        float xv[12];
        #pragma unroll
        for (int j = 0; j < 12; ++j) xv[j] = xptr[64 * j + lane];
        #pragma unroll
        for (int r = 0; r < 8; ++r) {
            int n = 64 * r + lane;
            float wn = wrow[n];
            float cn = basis[1025 * 1024 + n];
            float xa = xv[r], xb2 = xv[r + 4];
            z[r] = make_float2(wn * xa, wn * xb2);
            IA += cn * xa;  IB += cn * xb2;
            pA += (double)wn * (double)xa;  pB += (double)wn * (double)xb2;
        }
        #pragma unroll
        for (int j = 0; j < 4; ++j) xv[j] = xptr[64 * (12 + j) + lane];
        #pragma unroll
        for (int r = 8; r < 12; ++r) {
            int n = 64 * r + lane;
            float wn = wrow[n];
            float cn = basis[1025 * 1024 + n];
            float xa = xv[r], xb2 = xv[r - 8];
            z[r] = make_float2(wn * xa, wn * xb2);
            IA += cn * xa;  IB += cn * xb2;
            pA += (double)wn * (double)xa;  pB += (double)wn * (double)xb2;
        }
        #pragma unroll
        for (int j = 4; j < 8; ++j)
            xv[j] = has_b ? xptr[64 * (12 + j) + lane] : 0.0f;
        #pragma unroll
        for (int r = 12; r < 16; ++r) {
            int n = 64 * r + lane;
            float wn = wrow[n];
            float cn = basis[1025 * 1024 + n];
            float xa = xv[r - 12], xb2 = xv[r - 8];
            z[r] = make_float2(wn * xa, wn * xb2);
            IA += cn * xa;  IB += cn * xb2;
            pA += (double)wn * (double)xa;  pB += (double)wn * (double)xb2;
        }

        // ---- shared-pair reduction: DC = pair-sum, NyRe = pair-diff [R19]
        double qA = __shfl_xor(pA, 1), qB = __shfl_xor(pB, 1);
        double dcA = pA + qA, dcB = pB + qB;
        double nrA = (lane & 1) ? (qA - pA) : (pA - qA);
        double nrB = (lane & 1) ? (qB - pB) : (pB - qB);
        #pragma unroll
        for (int off = 2; off <= 32; off <<= 1) {
            dcA += __shfl_xor(dcA, off); dcB += __shfl_xor(dcB, off);
            nrA += __shfl_xor(nrA, off); nrB += __shfl_xor(nrB, off);
        }
        #pragma unroll
        for (int off = 32; off > 0; off >>= 1) {
            IA += __shfl_xor(IA, off); IB += __shfl_xor(IB, off);
        }

        // ---- stage 0: radix-4 DIF, stride 256 [R7-verified]
        #pragma unroll
        for (int r0 = 0; r0 < 4; ++r0) {
            float2 A = z[r0], B = z[r0 + 4], C = z[r0 + 8], D = z[r0 + 12];
            float t0r = A.x + C.x, t0i = A.y + C.y, t1r = A.x - C.x, t1i = A.y - C.y;
            float t2r = B.x + D.x, t2i = B.y + D.y, t3r = B.x - D.x, t3i = B.y - D.y;
            float nf = (float)(64 * r0 + lane);
            float2 w1 = twid(nf * (1.0f / 1024.0f));
            float2 w2 = twid(nf * (2.0f / 1024.0f));
            float2 w3 = twid(nf * (3.0f / 1024.0f));
            z[r0]      = make_float2(t0r + t2r, t0i + t2i);
            z[r0 + 4]  = cmulwf(t1r + t3i, t1i - t3r, w1);
            z[r0 + 8]  = cmulwf(t0r - t2r, t0i - t2i, w2);
            z[r0 + 12] = cmulwf(t1r - t3i, t1i + t3r, w3);
        }

        // ---- stage 1: radix-4 DIF, stride 64 [R7-verified]
        {
            float fl = (float)lane;
            float2 w1 = twid(fl * (4.0f / 1024.0f));
            float2 w2 = twid(fl * (8.0f / 1024.0f));
            float2 w3 = twid(fl * (12.0f / 1024.0f));
            #pragma unroll
            for (int g = 0; g < 4; ++g) {
                float2 A = z[4*g], B = z[4*g+1], C = z[4*g+2], D = z[4*g+3];
                float t0r = A.x + C.x, t0i = A.y + C.y, t1r = A.x - C.x, t1i = A.y - C.y;
                float t2r = B.x + D.x, t2i = B.y + D.y, t3r = B.x - D.x, t3i = B.y - D.y;
                z[4*g]     = make_float2(t0r + t2r, t0i + t2i);
                z[4*g + 1] = cmulwf(t1r + t3i, t1i - t3r, w1);
                z[4*g + 2] = cmulwf(t0r - t2r, t0i - t2i, w2);
                z[4*g + 3] = cmulwf(t1r - t3i, t1i + t3r, w3);
            }
        }

        // ---- stages 2..7: radix-2 across lanes, branchless [R7+R11-verified]
        #pragma unroll
        for (int st = 0; st < 6; ++st) {
            const int h = 32 >> st;
            const bool hi = (lane & h) != 0;
            float2 t = twid((float)(lane & (h - 1)) * ((float)(512 / h) * (1.0f / 1024.0f)));
            float wx = hi ? t.x : 1.0f;
            float wy = hi ? t.y : 0.0f;
            const float sgnD = hi ? -1.0f : 1.0f;
            #pragma unroll
            for (int r = 0; r < 16; ++r) {
                float vr = __shfl_xor(z[r].x, h);
                float vi = __shfl_xor(z[r].y, h);
                float sr = sgnD * z[r].x + vr;
                float si = sgnD * z[r].y + vi;
                z[r] = make_float2(sr * wx + si * wy, si * wx - sr * wy);
            }
        }

        // position (r,lane) holds bin k = 16*bitrev6(lane) + drev4(r).
        // Lane-pair epilogue [R9-verified] -> LDS staging.
        const int laneE = lane & ~1;
        const int RlE = bitrev6(laneE);
        const int lpA = bitrev6(63 - RlE);
        const int lpB = bitrev6((64 - RlE) & 63);
        const int SIG[16] = {0, 3, 2, 1, 15, 14, 13, 12, 11, 10, 9, 8, 7, 6, 5, 4};
        const bool isA = !(lane & 1);
        const bool okW = isA | has_b;
        const int myTT = ttA + (lane & 1);

        unsigned flags = 0;
        #pragma unroll
        for (int r = 0; r < 16; ++r) {
            const int lp = (r == 0) ? lpB : lpA;
            float ax = __shfl(z[r].x, laneE);
            float ay = __shfl(z[r].y, laneE);
            float px = __shfl(z[SIG[r]].x, lp);
            float py = __shfl(z[SIG[r]].y, lp);
            float rr = isA ? (ax + px) : (ay + py);
            float ii = isA ? (ay - py) : (px - ax);
            float rf  = 0.5f * rr;
            float iff = 0.5f * ii;
            const int rho = ((r & 3) << 2) | (r >> 2);
            const int k = 16 * RlE + rho;
            const int sl = slot17(k, myTT);
            smag[sl] = sqrtf(rf * rf + iff * iff);
            sph[sl]  = fast_atan2f(iff, rf);
            if (okW && __builtin_fabsf(iff) < FLAG_T && k != 0) flags |= (1u << r);
        }

        // ---- bin 0 (DC): im exactly +0; re from fp64 sum
        if (lane == 0) {
            float rf = (float)dcA, rf2 = (float)dcB;
            int s0 = slot17(0, ttA), s1 = slot17(0, ttA + 1);
            smag[s0] = __builtin_fabsf(rf);
            sph[s0]  = fast_atan2f(0.0f, rf);
            smag[s1] = __builtin_fabsf(rf2);
            sph[s1]  = fast_atan2f(0.0f, rf2);
        }
        // ---- bin 512 (Nyquist): re fp64 pair-diff sum, im exact dots
        if (lane == 1) {
            float rf = (float)nrA, rf2 = (float)nrB;
            int s0 = slot17(512, ttA), s1 = slot17(512, ttA + 1);
            smag[s0] = sqrtf(rf * rf + IA * IA);
            sph[s0]  = fast_atan2f(IA, rf);
            smag[s1] = sqrtf(rf2 * rf2 + IB * IB);
            sph[s1]  = fast_atan2f(IB, rf2);
        }

        // ---- repair loop: wave-cooperative exact fp64 dot per flagged bin
        unsigned long long wm = __ballot(flags != 0);
        while (wm) {
            int L = __ffsll((unsigned long long)wm) - 1;
            wm &= wm - 1;
            unsigned flL = __shfl(flags, L);
            const int kb = 16 * bitrev6(L & ~1);
            const int f  = L & 1;
            const float* px = xptr + f * HOP;
            while (flL) {
                int r = __ffs(flL) - 1;
                flL &= flL - 1;
                int k = kb + (((r & 3) << 2) | (r >> 2));
                double2 cur = wexp64((k * lane) & 1023);
                double2 S   = wexp64((k * 64) & 1023);
                double re = 0.0, im = 0.0;
                #pragma unroll
                for (int j = 0; j < 16; ++j) {
                    int n = 64 * j + lane;
                    double xw = (double)wrow[n] * (double)px[n];
                    re += xw * cur.x;
                    im -= xw * cur.y;
                    double nx = cur.x * S.x - cur.y * S.y;
                    double ny = cur.y * S.x + cur.x * S.y;
                    cur.x = nx; cur.y = ny;
                }
                #pragma unroll
                for (int off = 32; off > 0; off >>= 1) {
                    re += __shfl_xor(re, off);
                    im += __shfl_xor(im, off);
                }
                if (lane == L) {
                    int sl = slot17(k, ttA + f);
                    smag[sl] = sqrtf((float)(re * re + im * im));
                    sph[sl]  = fast_atan2f((float)im, (float)re);
                }
            }
        }
    }

    __syncthreads();

    // ---- flush: 16-t-wide coalesced runs (one k-line segment per block)
    float* omag = out + (size_t)b * CUT * T_FRAMES;
    float* oph  = omag + (size_t)BATCH * CUT * T_FRAMES;
    for (int f = tid; f < CUT * 16; f += 512) {
        int k = f >> 4, tt = f & 15;
        int t = tb + tt;
        if (t < T_FRAMES) {
            int sl = slot17(k, tt);
            size_t g = (size_t)k * T_FRAMES + t;
            omag[g] = smag[sl];
            oph[g]  = sph[sl];
        }
    }
}

extern "C" void kernel_launch(void* const* d_in, const int* in_sizes, int n_in,
                              void* d_out, int out_size, void* d_ws, size_t ws_size,
                              hipStream_t stream) {
    (void)in_sizes; (void)n_in; (void)d_ws; (void)ws_size; (void)out_size;
    const float* x     = (const float*)d_in[0];
    const float* basis = (const float*)d_in[1];
    float* out = (float*)d_out;
    dim3 grid(NWG);     // 1024 blocks x 8 waves, 16 frames per block
    dim3 block(512);
    stft_fft_kernel<<<grid, block, 0, stream>>>(x, basis, out);
}

// Round 21
// 54.988 us; speedup vs baseline: 1.2763x; 1.2763x over previous
//
#include <hip/hip_runtime.h>

#define HOP 256
#define CUT 513
#define T_FRAMES 1021
#define N_SAMPLES 262144
#define BATCH 16
#define NPAIR 511                 // frame pairs per batch (last pair is lone)
#define NWG 2044                  // 8176 wave-tasks / 4 waves per block
#define FLAG_T 0.01f              // |im| flag threshold (fp32 FFT err ~2e-4)

// 6-bit bit reversal
__device__ __forceinline__ int bitrev6(int v) {
    return ((v & 1) << 5) | ((v & 2) << 3) | ((v & 4) << 1)
         | ((v & 8) >> 1) | ((v & 16) >> 3) | ((v & 32) >> 5);
}
// LDS slot for (k, tt in 0..7): stride 9 + XOR swizzle [R17-verified]
__device__ __forceinline__ int slotOf(int k, int tt) {
    return 9 * k + (tt ^ ((k >> 4) & 7));
}
// W_1024^k as (cos,sin), arg in revolutions [R7-verified]
__device__ __forceinline__ float2 twid(float rev) {
    return make_float2(__builtin_amdgcn_cosf(rev), __builtin_amdgcn_sinf(rev));
}
__device__ __forceinline__ float2 cmulwf(float yr, float yi, float2 w) {
    return make_float2(yr * w.x + yi * w.y, yi * w.x - yr * w.y);
}
// fast atan2 [R13-verified]
__device__ __forceinline__ float fast_atan2f(float y, float x) {
    const float PI  = 3.14159265358979323846f;
    const float PI2 = 1.57079632679489661923f;
    float ay = __builtin_fabsf(y), ax = __builtin_fabsf(x);
    float mx = fmaxf(ax, ay), mn = fminf(ax, ay);
    float r  = mn * __builtin_amdgcn_rcpf(mx);
    float s  = r * r;
    float p  = r * (0.99997726f + s * (-0.33262347f + s * (0.19354346f
             + s * (-0.11643287f + s * (0.05265332f + s * (-0.01172120f))))));
    p = (ay > ax) ? (PI2 - p) : p;
    p = (x < 0.0f) ? (PI - p) : p;
    return __builtin_copysignf(p, y);
}
// fp64 (cos,sin) of 2*pi*e/1024 [R16-verified]
__device__ __forceinline__ double2 wexp64(int e) {
    const int d = e & 63, c = (e >> 6) & 3, a = (e >> 8) & 3;
    double xx = (6.2831853071795864769252867665590057684 / 1024.0) * (double)d;
    double x2 = xx * xx;
    double cc = 1.0 + x2 * (-0.5 + x2 * (1.0/24.0 + x2 * (-1.0/720.0
               + x2 * (1.0/40320.0 + x2 * (-1.0/3628800.0)))));
    double ss = xx * (1.0 + x2 * (-1.0/6.0 + x2 * (1.0/120.0 + x2 * (-1.0/5040.0
               + x2 * (1.0/362880.0 + x2 * (-1.0/39916800.0))))));
    double kc = (c == 0) ? 1.0
              : (c == 1) ? 0.92387953251128675612818318939679
              : (c == 2) ? 0.70710678118654752440084436210485
                         : 0.38268343236508977172845998403040;
    double ks = (c == 0) ? 0.0
              : (c == 1) ? 0.38268343236508977172845998403040
              : (c == 2) ? 0.70710678118654752440084436210485
                         : 0.92387953251128675612818318939679;
    double cr = cc * kc - ss * ks;
    double ci = ss * kc + cc * ks;
    double2 r;
    r.x = (a == 0) ? cr : ((a == 1) ? -ci : ((a == 2) ? -cr : ci));
    r.y = (a == 0) ? ci : ((a == 1) ?  cr : ((a == 2) ? -ci : -cr));
    return r;
}

__global__ __launch_bounds__(256, 4) void stft_fft_kernel(
    const float* __restrict__ x,
    const float* __restrict__ basis,
    float* __restrict__ out)
{
    __shared__ float smag[9 * CUT + 8];   // slotOf-addressed [k][tt]
    __shared__ float sph[9 * CUT + 8];

    const int tid  = threadIdx.x;
    const int lane = tid & 63;
    const int wv   = tid >> 6;

    // bijective XCD-chunked swizzle (NWG % 8 == 4); 4 consecutive pairs/block
    const int q8 = NWG >> 3, rem = NWG & 7;
    const int xcd = blockIdx.x & 7, idx = blockIdx.x >> 3;
    const int sb = (xcd < rem) ? (xcd * (q8 + 1) + idx)
                               : (rem * (q8 + 1) + (xcd - rem) * q8 + idx);
    const int task = sb * 4 + wv;
    const int b  = task / NPAIR;
    const int pr = task - b * NPAIR;
    const int t0 = 2 * pr;
    const bool has_b = (t0 + 1 < T_FRAMES);
    const int ttA = 2 * wv;               // this wave's LDS columns

    const float* xptr = x + (size_t)b * N_SAMPLES + (size_t)t0 * HOP;
    const float* wrow = basis;                          // row 0 == Hann window

    // ---- 8-reg rolling-window load (reg-pressure cut vs R19's 12)
    // phase plan: j=0..7 -> r=0..3 | j=8..11 over slots0..3 -> r=4..7 |
    // j=12..15 over slots4..7 -> r=8..11 | j=16..19 over slots0..3 -> r=12..15
    float2 z[16];
    float IA = 0.f, IB = 0.f;
    double pA = 0.0, pB = 0.0;            // per-lane fp64 partial of sum(w*x)
    float xv[8];
    #pragma unroll
    for (int j = 0; j < 8; ++j) xv[j] = xptr[64 * j + lane];
    #pragma unroll
    for (int r = 0; r < 4; ++r) {         // xa: slot r (j=r), xb: slot r+4 (j=r+4)
        int n = 64 * r + lane;
        float wn = wrow[n];
        float cn = basis[1025 * 1024 + n];
        float xa = xv[r], xb2 = xv[r + 4];
        z[r] = make_float2(wn * xa, wn * xb2);
        IA += cn * xa;  IB += cn * xb2;
        pA += (double)wn * (double)xa;  pB += (double)wn * (double)xb2;
    }
    #pragma unroll
    for (int j = 0; j < 4; ++j) xv[j] = xptr[64 * (8 + j) + lane];     // j=8..11
    #pragma unroll
    for (int r = 4; r < 8; ++r) {         // xa: slot r (j=r), xb: slot r-4 (j=r+4)
        int n = 64 * r + lane;
        float wn = wrow[n];
        float cn = basis[1025 * 1024 + n];
        float xa = xv[r], xb2 = xv[r - 4];
        z[r] = make_float2(wn * xa, wn * xb2);
        IA += cn * xa;  IB += cn * xb2;
        pA += (double)wn * (double)xa;  pB += (double)wn * (double)xb2;
    }
    #pragma unroll
    for (int j = 4; j < 8; ++j) xv[j] = xptr[64 * (8 + j) + lane];     // j=12..15
    #pragma unroll
    for (int r = 8; r < 12; ++r) {        // xa: slot r-8 (j=r), xb: slot r-4 (j=r+4)
        int n = 64 * r + lane;
        float wn = wrow[n];
        float cn = basis[1025 * 1024 + n];
        float xa = xv[r - 8], xb2 = xv[r - 4];
        z[r] = make_float2(wn * xa, wn * xb2);
        IA += cn * xa;  IB += cn * xb2;
        pA += (double)wn * (double)xa;  pB += (double)wn * (double)xb2;
    }
    #pragma unroll
    for (int j = 0; j < 4; ++j)           // j=16..19, frame-B only
        xv[j] = has_b ? xptr[64 * (16 + j) + lane] : 0.0f;
    #pragma unroll
    for (int r = 12; r < 16; ++r) {       // xa: slot r-8 (j=r), xb: slot r-12 (j=r+4)
        int n = 64 * r + lane;
        float wn = wrow[n];
        float cn = basis[1025 * 1024 + n];
        float xa = xv[r - 8], xb2 = xv[r - 12];
        z[r] = make_float2(wn * xa, wn * xb2);
        IA += cn * xa;  IB += cn * xb2;
        pA += (double)wn * (double)xa;  pB += (double)wn * (double)xb2;
    }

    // ---- shared-pair reduction: DC = pair-sum, NyRe = pair-diff [R19-verified]
    double qA = __shfl_xor(pA, 1), qB = __shfl_xor(pB, 1);
    double dcA = pA + qA, dcB = pB + qB;
    double nrA = (lane & 1) ? (qA - pA) : (pA - qA);
    double nrB = (lane & 1) ? (qB - pB) : (pB - qB);
    #pragma unroll
    for (int off = 2; off <= 32; off <<= 1) {
        dcA += __shfl_xor(dcA, off); dcB += __shfl_xor(dcB, off);
        nrA += __shfl_xor(nrA, off); nrB += __shfl_xor(nrB, off);
    }
    #pragma unroll
    for (int off = 32; off > 0; off >>= 1) {
        IA += __shfl_xor(IA, off); IB += __shfl_xor(IB, off);
    }

    // ---- stage 0: radix-4 DIF, stride 256 (in-lane) [R7-verified]
    #pragma unroll
    for (int r0 = 0; r0 < 4; ++r0) {
        float2 A = z[r0], B = z[r0 + 4], C = z[r0 + 8], D = z[r0 + 12];
        float t0r = A.x + C.x, t0i = A.y + C.y, t1r = A.x - C.x, t1i = A.y - C.y;
        float t2r = B.x + D.x, t2i = B.y + D.y, t3r = B.x - D.x, t3i = B.y - D.y;
        float nf = (float)(64 * r0 + lane);
        float2 w1 = twid(nf * (1.0f / 1024.0f));
        float2 w2 = twid(nf * (2.0f / 1024.0f));
        float2 w3 = twid(nf * (3.0f / 1024.0f));
        z[r0]      = make_float2(t0r + t2r, t0i + t2i);
        z[r0 + 4]  = cmulwf(t1r + t3i, t1i - t3r, w1);
        z[r0 + 8]  = cmulwf(t0r - t2r, t0i - t2i, w2);
        z[r0 + 12] = cmulwf(t1r - t3i, t1i + t3r, w3);
    }

    // ---- stage 1: radix-4 DIF, stride 64 (in-lane) [R7-verified]
    {
        float fl = (float)lane;
        float2 w1 = twid(fl * (4.0f / 1024.0f));
        float2 w2 = twid(fl * (8.0f / 1024.0f));
        float2 w3 = twid(fl * (12.0f / 1024.0f));
        #pragma unroll
        for (int g = 0; g < 4; ++g) {
            float2 A = z[4*g], B = z[4*g+1], C = z[4*g+2], D = z[4*g+3];
            float t0r = A.x + C.x, t0i = A.y + C.y, t1r = A.x - C.x, t1i = A.y - C.y;
            float t2r = B.x + D.x, t2i = B.y + D.y, t3r = B.x - D.x, t3i = B.y - D.y;
            z[4*g]     = make_float2(t0r + t2r, t0i + t2i);
            z[4*g + 1] = cmulwf(t1r + t3i, t1i - t3r, w1);
            z[4*g + 2] = cmulwf(t0r - t2r, t0i - t2i, w2);
            z[4*g + 3] = cmulwf(t1r - t3i, t1i + t3r, w3);
        }
    }

    // ---- stages 2..7: radix-2 DIF across lanes, branchless [R7+R11-verified]
    #pragma unroll
    for (int st = 0; st < 6; ++st) {
        const int h = 32 >> st;
        const bool hi = (lane & h) != 0;
        float2 t = twid((float)(lane & (h - 1)) * ((float)(512 / h) * (1.0f / 1024.0f)));
        float wx = hi ? t.x : 1.0f;
        float wy = hi ? t.y : 0.0f;
        const float sgnD = hi ? -1.0f : 1.0f;
        #pragma unroll
        for (int r = 0; r < 16; ++r) {
            float vr = __shfl_xor(z[r].x, h);
            float vi = __shfl_xor(z[r].y, h);
            float sr = sgnD * z[r].x + vr;
            float si = sgnD * z[r].y + vi;
            z[r] = make_float2(sr * wx + si * wy, si * wx - sr * wy);
        }
    }

    // position (r,lane) holds bin k = 16*bitrev6(lane) + drev4(r).
    // Lane-pair epilogue [R9-verified] -> LDS staging.
    const int laneE = lane & ~1;
    const int RlE = bitrev6(laneE);               // < 32
    const int lpA = bitrev6(63 - RlE);
    const int lpB = bitrev6((64 - RlE) & 63);
    const int SIG[16] = {0, 3, 2, 1, 15, 14, 13, 12, 11, 10, 9, 8, 7, 6, 5, 4};
    const bool isA = !(lane & 1);
    const bool okW = isA | has_b;
    const int myTT = ttA + (lane & 1);

    unsigned flags = 0;
    #pragma unroll
    for (int r = 0; r < 16; ++r) {
        const int lp = (r == 0) ? lpB : lpA;
        float ax = __shfl(z[r].x, laneE);
        float ay = __shfl(z[r].y, laneE);
        float px = __shfl(z[SIG[r]].x, lp);
        float py = __shfl(z[SIG[r]].y, lp);
        float rr = isA ? (ax + px) : (ay + py);
        float ii = isA ? (ay - py) : (px - ax);
        float rf  = 0.5f * rr;
        float iff = 0.5f * ii;
        const int rho = ((r & 3) << 2) | (r >> 2);
        const int k = 16 * RlE + rho;
        const int sl = slotOf(k, myTT);
        smag[sl] = sqrtf(rf * rf + iff * iff);
        sph[sl]  = fast_atan2f(iff, rf);
        if (okW && __builtin_fabsf(iff) < FLAG_T && k != 0) flags |= (1u << r);
    }

    // ---- bin 0 (DC): im exactly +0; re from fp64 sum
    if (lane == 0) {
        float rf = (float)dcA, rf2 = (float)dcB;
        int s0 = slotOf(0, ttA), s1 = slotOf(0, ttA + 1);
        smag[s0] = __builtin_fabsf(rf);
        sph[s0]  = fast_atan2f(0.0f, rf);
        smag[s1] = __builtin_fabsf(rf2);
        sph[s1]  = fast_atan2f(0.0f, rf2);
    }
    // ---- bin 512 (Nyquist): re fp64 pair-difference sum, im exact dots
    if (lane == 1) {
        float rf = (float)nrA, rf2 = (float)nrB;
        int s0 = slotOf(512, ttA), s1 = slotOf(512, ttA + 1);
        smag[s0] = sqrtf(rf * rf + IA * IA);
        sph[s0]  = fast_atan2f(IA, rf);
        smag[s1] = sqrtf(rf2 * rf2 + IB * IB);
        sph[s1]  = fast_atan2f(IB, rf2);
    }

    // ---- repair loop: wave-cooperative exact fp64 dot per flagged bin
    unsigned long long wm = __ballot(flags != 0);
    while (wm) {
        int L = __ffsll((unsigned long long)wm) - 1;
        wm &= wm - 1;
        unsigned flL = __shfl(flags, L);
        const int kb = 16 * bitrev6(L & ~1);
        const int f  = L & 1;
        const float* px = xptr + f * HOP;
        while (flL) {
            int r = __ffs(flL) - 1;
            flL &= flL - 1;
            int k = kb + (((r & 3) << 2) | (r >> 2));
            double2 cur = wexp64((k * lane) & 1023);
            double2 S   = wexp64((k * 64) & 1023);
            double re = 0.0, im = 0.0;
            #pragma unroll
            for (int j = 0; j < 16; ++j) {
                int n = 64 * j + lane;
                double xw = (double)wrow[n] * (double)px[n];
                re += xw * cur.x;
                im -= xw * cur.y;
                double nx = cur.x * S.x - cur.y * S.y;
                double ny = cur.y * S.x + cur.x * S.y;
                cur.x = nx; cur.y = ny;
            }
            #pragma unroll
            for (int off = 32; off > 0; off >>= 1) {
                re += __shfl_xor(re, off);
                im += __shfl_xor(im, off);
            }
            if (lane == L) {
                int sl = slotOf(k, ttA + f);
                smag[sl] = sqrtf((float)(re * re + im * im));
                sph[sl]  = fast_atan2f((float)im, (float)re);
            }
        }
    }

    __syncthreads();

    // ---- flush: coalesced 8-t-wide runs; per-column (b,t) recomputed
    const size_t PH = (size_t)BATCH * CUT * T_FRAMES;
    for (int f = tid; f < CUT * 8; f += 256) {
        int k = f >> 3, ttx = f & 7;
        int task_w = sb * 4 + (ttx >> 1);
        int bw  = task_w / NPAIR;
        int prw = task_w - bw * NPAIR;
        int tw  = 2 * prw + (ttx & 1);
        if (tw < T_FRAMES) {
            int sl = slotOf(k, ttx);
            size_t g = (size_t)bw * CUT * T_FRAMES + (size_t)k * T_FRAMES + tw;
            out[g]      = smag[sl];
            out[g + PH] = sph[sl];
        }
    }
}

extern "C" void kernel_launch(void* const* d_in, const int* in_sizes, int n_in,
                              void* d_out, int out_size, void* d_ws, size_t ws_size,
                              hipStream_t stream) {
    (void)in_sizes; (void)n_in; (void)d_ws; (void)ws_size; (void)out_size;
    const float* x     = (const float*)d_in[0];
    const float* basis = (const float*)d_in[1];
    float* out = (float*)d_out;
    dim3 grid(NWG);     // 2044 blocks x 4 waves
    dim3 block(256);
    stft_fft_kernel<<<grid, block, 0, stream>>>(x, basis, out);
}

// Round 22
// 54.978 us; speedup vs baseline: 1.2765x; 1.0002x over previous
//
#include <hip/hip_runtime.h>
#include <hip/hip_fp16.h>

#define HOP 256
#define CUT 513
#define T_FRAMES 1021
#define N_SAMPLES 262144
#define BATCH 16
#define NPAIR 511                 // frame pairs per batch (last pair is lone)
#define NWG 2044                  // 8176 wave-tasks / 4 waves per block
#define FLAG_T 0.01f              // |im| flag threshold (fp32 FFT err ~2e-4)

// 6-bit bit reversal
__device__ __forceinline__ int bitrev6(int v) {
    return ((v & 1) << 5) | ((v & 2) << 3) | ((v & 4) << 1)
         | ((v & 8) >> 1) | ((v & 16) >> 3) | ((v & 32) >> 5);
}
// LDS slot for (k, tt in 0..7): stride 9 + XOR swizzle [R17-verified]
__device__ __forceinline__ int slotOf(int k, int tt) {
    return 9 * k + (tt ^ ((k >> 4) & 7));
}
// W_1024^k as (cos,sin), arg in revolutions [R7-verified]
__device__ __forceinline__ float2 twid(float rev) {
    return make_float2(__builtin_amdgcn_cosf(rev), __builtin_amdgcn_sinf(rev));
}
__device__ __forceinline__ float2 cmulwf(float yr, float yi, float2 w) {
    return make_float2(yr * w.x + yi * w.y, yi * w.x - yr * w.y);
}
// fast atan2 [R13-verified]
__device__ __forceinline__ float fast_atan2f(float y, float x) {
    const float PI  = 3.14159265358979323846f;
    const float PI2 = 1.57079632679489661923f;
    float ay = __builtin_fabsf(y), ax = __builtin_fabsf(x);
    float mx = fmaxf(ax, ay), mn = fminf(ax, ay);
    float r  = mn * __builtin_amdgcn_rcpf(mx);
    float s  = r * r;
    float p  = r * (0.99997726f + s * (-0.33262347f + s * (0.19354346f
             + s * (-0.11643287f + s * (0.05265332f + s * (-0.01172120f))))));
    p = (ay > ax) ? (PI2 - p) : p;
    p = (x < 0.0f) ? (PI - p) : p;
    return __builtin_copysignf(p, y);
}
// fp64 (cos,sin) of 2*pi*e/1024 [R16-verified]
__device__ __forceinline__ double2 wexp64(int e) {
    const int d = e & 63, c = (e >> 6) & 3, a = (e >> 8) & 3;
    double xx = (6.2831853071795864769252867665590057684 / 1024.0) * (double)d;
    double x2 = xx * xx;
    double cc = 1.0 + x2 * (-0.5 + x2 * (1.0/24.0 + x2 * (-1.0/720.0
               + x2 * (1.0/40320.0 + x2 * (-1.0/3628800.0)))));
    double ss = xx * (1.0 + x2 * (-1.0/6.0 + x2 * (1.0/120.0 + x2 * (-1.0/5040.0
               + x2 * (1.0/362880.0 + x2 * (-1.0/39916800.0))))));
    double kc = (c == 0) ? 1.0
              : (c == 1) ? 0.92387953251128675612818318939679
              : (c == 2) ? 0.70710678118654752440084436210485
                         : 0.38268343236508977172845998403040;
    double ks = (c == 0) ? 0.0
              : (c == 1) ? 0.38268343236508977172845998403040
              : (c == 2) ? 0.70710678118654752440084436210485
                         : 0.92387953251128675612818318939679;
    double cr = cc * kc - ss * ks;
    double ci = ss * kc + cc * ks;
    double2 r;
    r.x = (a == 0) ? cr : ((a == 1) ? -ci : ((a == 2) ? -cr : ci));
    r.y = (a == 0) ? ci : ((a == 1) ?  cr : ((a == 2) ? -ci : -cr));
    return r;
}

__global__ __launch_bounds__(256, 4) void stft_fft_kernel(
    const float* __restrict__ x,
    const float* __restrict__ basis,
    float* __restrict__ out)
{
    // fp16-packed staging: .x = magnitude, .y = phase. Halves LDS vs two
    // fp32 buffers -> 8 blocks/CU (LDS was the occupancy governor).
    // Numerics: mag <= ~100 -> fp16 abs err <= ~0.05; phase err <= 1.6e-3;
    // both << 1.72 threshold. Flags/repair use fp32 values pre-staging.
    __shared__ __half2 sbuf[9 * CUT + 8];

    const int tid  = threadIdx.x;
    const int lane = tid & 63;
    const int wv   = tid >> 6;

    // bijective XCD-chunked swizzle (NWG % 8 == 4); 4 consecutive pairs/block
    const int q8 = NWG >> 3, rem = NWG & 7;
    const int xcd = blockIdx.x & 7, idx = blockIdx.x >> 3;
    const int sb = (xcd < rem) ? (xcd * (q8 + 1) + idx)
                               : (rem * (q8 + 1) + (xcd - rem) * q8 + idx);
    const int task = sb * 4 + wv;
    const int b  = task / NPAIR;
    const int pr = task - b * NPAIR;
    const int t0 = 2 * pr;
    const bool has_b = (t0 + 1 < T_FRAMES);
    const int ttA = 2 * wv;               // this wave's LDS columns

    const float* xptr = x + (size_t)b * N_SAMPLES + (size_t)t0 * HOP;
    const float* wrow = basis;                          // row 0 == Hann window

    // ---- 8-reg rolling-window load [R21-verified]
    float2 z[16];
    float IA = 0.f, IB = 0.f;
    double pA = 0.0, pB = 0.0;            // per-lane fp64 partial of sum(w*x)
    float xv[8];
    #pragma unroll
    for (int j = 0; j < 8; ++j) xv[j] = xptr[64 * j + lane];
    #pragma unroll
    for (int r = 0; r < 4; ++r) {
        int n = 64 * r + lane;
        float wn = wrow[n];
        float cn = basis[1025 * 1024 + n];
        float xa = xv[r], xb2 = xv[r + 4];
        z[r] = make_float2(wn * xa, wn * xb2);
        IA += cn * xa;  IB += cn * xb2;
        pA += (double)wn * (double)xa;  pB += (double)wn * (double)xb2;
    }
    #pragma unroll
    for (int j = 0; j < 4; ++j) xv[j] = xptr[64 * (8 + j) + lane];     // j=8..11
    #pragma unroll
    for (int r = 4; r < 8; ++r) {
        int n = 64 * r + lane;
        float wn = wrow[n];
        float cn = basis[1025 * 1024 + n];
        float xa = xv[r], xb2 = xv[r - 4];
        z[r] = make_float2(wn * xa, wn * xb2);
        IA += cn * xa;  IB += cn * xb2;
        pA += (double)wn * (double)xa;  pB += (double)wn * (double)xb2;
    }
    #pragma unroll
    for (int j = 4; j < 8; ++j) xv[j] = xptr[64 * (8 + j) + lane];     // j=12..15
    #pragma unroll
    for (int r = 8; r < 12; ++r) {
        int n = 64 * r + lane;
        float wn = wrow[n];
        float cn = basis[1025 * 1024 + n];
        float xa = xv[r - 8], xb2 = xv[r - 4];
        z[r] = make_float2(wn * xa, wn * xb2);
        IA += cn * xa;  IB += cn * xb2;
        pA += (double)wn * (double)xa;  pB += (double)wn * (double)xb2;
    }
    #pragma unroll
    for (int j = 0; j < 4; ++j)           // j=16..19, frame-B only
        xv[j] = has_b ? xptr[64 * (16 + j) + lane] : 0.0f;
    #pragma unroll
    for (int r = 12; r < 16; ++r) {
        int n = 64 * r + lane;
        float wn = wrow[n];
        float cn = basis[1025 * 1024 + n];
        float xa = xv[r - 8], xb2 = xv[r - 12];
        z[r] = make_float2(wn * xa, wn * xb2);
        IA += cn * xa;  IB += cn * xb2;
        pA += (double)wn * (double)xa;  pB += (double)wn * (double)xb2;
    }

    // ---- shared-pair reduction: DC = pair-sum, NyRe = pair-diff [R19-verified]
    double qA = __shfl_xor(pA, 1), qB = __shfl_xor(pB, 1);
    double dcA = pA + qA, dcB = pB + qB;
    double nrA = (lane & 1) ? (qA - pA) : (pA - qA);
    double nrB = (lane & 1) ? (qB - pB) : (pB - qB);
    #pragma unroll
    for (int off = 2; off <= 32; off <<= 1) {
        dcA += __shfl_xor(dcA, off); dcB += __shfl_xor(dcB, off);
        nrA += __shfl_xor(nrA, off); nrB += __shfl_xor(nrB, off);
    }
    #pragma unroll
    for (int off = 32; off > 0; off >>= 1) {
        IA += __shfl_xor(IA, off); IB += __shfl_xor(IB, off);
    }

    // ---- stage 0: radix-4 DIF, stride 256 (in-lane) [R7-verified]
    #pragma unroll
    for (int r0 = 0; r0 < 4; ++r0) {
        float2 A = z[r0], B = z[r0 + 4], C = z[r0 + 8], D = z[r0 + 12];
        float t0r = A.x + C.x, t0i = A.y + C.y, t1r = A.x - C.x, t1i = A.y - C.y;
        float t2r = B.x + D.x, t2i = B.y + D.y, t3r = B.x - D.x, t3i = B.y - D.y;
        float nf = (float)(64 * r0 + lane);
        float2 w1 = twid(nf * (1.0f / 1024.0f));
        float2 w2 = twid(nf * (2.0f / 1024.0f));
        float2 w3 = twid(nf * (3.0f / 1024.0f));
        z[r0]      = make_float2(t0r + t2r, t0i + t2i);
        z[r0 + 4]  = cmulwf(t1r + t3i, t1i - t3r, w1);
        z[r0 + 8]  = cmulwf(t0r - t2r, t0i - t2i, w2);
        z[r0 + 12] = cmulwf(t1r - t3i, t1i + t3r, w3);
    }

    // ---- stage 1: radix-4 DIF, stride 64 (in-lane) [R7-verified]
    {
        float fl = (float)lane;
        float2 w1 = twid(fl * (4.0f / 1024.0f));
        float2 w2 = twid(fl * (8.0f / 1024.0f));
        float2 w3 = twid(fl * (12.0f / 1024.0f));
        #pragma unroll
        for (int g = 0; g < 4; ++g) {
            float2 A = z[4*g], B = z[4*g+1], C = z[4*g+2], D = z[4*g+3];
            float t0r = A.x + C.x, t0i = A.y + C.y, t1r = A.x - C.x, t1i = A.y - C.y;
            float t2r = B.x + D.x, t2i = B.y + D.y, t3r = B.x - D.x, t3i = B.y - D.y;
            z[4*g]     = make_float2(t0r + t2r, t0i + t2i);
            z[4*g + 1] = cmulwf(t1r + t3i, t1i - t3r, w1);
            z[4*g + 2] = cmulwf(t0r - t2r, t0i - t2i, w2);
            z[4*g + 3] = cmulwf(t1r - t3i, t1i + t3r, w3);
        }
    }

    // ---- stages 2..7: radix-2 DIF across lanes, branchless [R7+R11-verified]
    #pragma unroll
    for (int st = 0; st < 6; ++st) {
        const int h = 32 >> st;
        const bool hi = (lane & h) != 0;
        float2 t = twid((float)(lane & (h - 1)) * ((float)(512 / h) * (1.0f / 1024.0f)));
        float wx = hi ? t.x : 1.0f;
        float wy = hi ? t.y : 0.0f;
        const float sgnD = hi ? -1.0f : 1.0f;
        #pragma unroll
        for (int r = 0; r < 16; ++r) {
            float vr = __shfl_xor(z[r].x, h);
            float vi = __shfl_xor(z[r].y, h);
            float sr = sgnD * z[r].x + vr;
            float si = sgnD * z[r].y + vi;
            z[r] = make_float2(sr * wx + si * wy, si * wx - sr * wy);
        }
    }

    // position (r,lane) holds bin k = 16*bitrev6(lane) + drev4(r).
    // Lane-pair epilogue [R9-verified] -> packed fp16 LDS staging.
    const int laneE = lane & ~1;
    const int RlE = bitrev6(laneE);               // < 32
    const int lpA = bitrev6(63 - RlE);
    const int lpB = bitrev6((64 - RlE) & 63);
    const int SIG[16] = {0, 3, 2, 1, 15, 14, 13, 12, 11, 10, 9, 8, 7, 6, 5, 4};
    const bool isA = !(lane & 1);
    const bool okW = isA | has_b;
    const int myTT = ttA + (lane & 1);

    unsigned flags = 0;
    #pragma unroll
    for (int r = 0; r < 16; ++r) {
        const int lp = (r == 0) ? lpB : lpA;
        float ax = __shfl(z[r].x, laneE);
        float ay = __shfl(z[r].y, laneE);
        float px = __shfl(z[SIG[r]].x, lp);
        float py = __shfl(z[SIG[r]].y, lp);
        float rr = isA ? (ax + px) : (ay + py);
        float ii = isA ? (ay - py) : (px - ax);
        float rf  = 0.5f * rr;
        float iff = 0.5f * ii;
        const int rho = ((r & 3) << 2) | (r >> 2);
        const int k = 16 * RlE + rho;
        sbuf[slotOf(k, myTT)] = __floats2half2_rn(
            sqrtf(rf * rf + iff * iff), fast_atan2f(iff, rf));
        if (okW && __builtin_fabsf(iff) < FLAG_T && k != 0) flags |= (1u << r);
    }

    // ---- bin 0 (DC): im exactly +0; re from fp64 sum
    if (lane == 0) {
        float rf = (float)dcA, rf2 = (float)dcB;
        sbuf[slotOf(0, ttA)]     = __floats2half2_rn(__builtin_fabsf(rf),
                                                     fast_atan2f(0.0f, rf));
        sbuf[slotOf(0, ttA + 1)] = __floats2half2_rn(__builtin_fabsf(rf2),
                                                     fast_atan2f(0.0f, rf2));
    }
    // ---- bin 512 (Nyquist): re fp64 pair-difference sum, im exact dots
    if (lane == 1) {
        float rf = (float)nrA, rf2 = (float)nrB;
        sbuf[slotOf(512, ttA)]     = __floats2half2_rn(sqrtf(rf * rf + IA * IA),
                                                       fast_atan2f(IA, rf));
        sbuf[slotOf(512, ttA + 1)] = __floats2half2_rn(sqrtf(rf2 * rf2 + IB * IB),
                                                       fast_atan2f(IB, rf2));
    }

    // ---- repair loop: wave-cooperative exact fp64 dot per flagged bin
    unsigned long long wm = __ballot(flags != 0);
    while (wm) {
        int L = __ffsll((unsigned long long)wm) - 1;
        wm &= wm - 1;
        unsigned flL = __shfl(flags, L);
        const int kb = 16 * bitrev6(L & ~1);
        const int f  = L & 1;
        const float* px = xptr + f * HOP;
        while (flL) {
            int r = __ffs(flL) - 1;
            flL &= flL - 1;
            int k = kb + (((r & 3) << 2) | (r >> 2));
            double2 cur = wexp64((k * lane) & 1023);
            double2 S   = wexp64((k * 64) & 1023);
            double re = 0.0, im = 0.0;
            #pragma unroll
            for (int j = 0; j < 16; ++j) {
                int n = 64 * j + lane;
                double xw = (double)wrow[n] * (double)px[n];
                re += xw * cur.x;
                im -= xw * cur.y;
                double nx = cur.x * S.x - cur.y * S.y;
                double ny = cur.y * S.x + cur.x * S.y;
                cur.x = nx; cur.y = ny;
            }
            #pragma unroll
            for (int off = 32; off > 0; off >>= 1) {
                re += __shfl_xor(re, off);
                im += __shfl_xor(im, off);
            }
            if (lane == L) {
                sbuf[slotOf(k, ttA + f)] = __floats2half2_rn(
                    sqrtf((float)(re * re + im * im)),
                    fast_atan2f((float)im, (float)re));
            }
        }
    }

    __syncthreads();

    // ---- flush: coalesced 8-t-wide runs; per-column (b,t) recomputed
    const size_t PH = (size_t)BATCH * CUT * T_FRAMES;
    for (int f = tid; f < CUT * 8; f += 256) {
        int k = f >> 3, ttx = f & 7;
        int task_w = sb * 4 + (ttx >> 1);
        int bw  = task_w / NPAIR;
        int prw = task_w - bw * NPAIR;
        int tw  = 2 * prw + (ttx & 1);
        if (tw < T_FRAMES) {
            __half2 v = sbuf[slotOf(k, ttx)];
            size_t g = (size_t)bw * CUT * T_FRAMES + (size_t)k * T_FRAMES + tw;
            out[g]      = __low2float(v);
            out[g + PH] = __high2float(v);
        }
    }
}

extern "C" void kernel_launch(void* const* d_in, const int* in_sizes, int n_in,
                              void* d_out, int out_size, void* d_ws, size_t ws_size,
                              hipStream_t stream) {
    (void)in_sizes; (void)n_in; (void)d_ws; (void)ws_size; (void)out_size;
    const float* x     = (const float*)d_in[0];
    const float* basis = (const float*)d_in[1];
    float* out = (float*)d_out;
    dim3 grid(NWG);     // 2044 blocks x 4 waves
    dim3 block(256);
    stft_fft_kernel<<<grid, block, 0, stream>>>(x, basis, out);
}